// Round 1
// baseline (1121.550 us; speedup 1.0000x reference)
//
#include <hip/hip_runtime.h>

#define N_NODES 100000
#define N_EDGES 1200000
#define FEAT    64
#define ATTR_D  32
#define HID     (4 * FEAT)

// ---------------------------------------------------------------------------
// Stage 1: per-edge depthwise kernel + gather-multiply + scatter-add.
// One wave per edge: lane = output feature. Edge index is wave-uniform
// (grid stride is a multiple of 64), readfirstlane forces it to SGPR so
// attr row + src/dst become scalar loads.
// ---------------------------------------------------------------------------
__global__ void edge_kernel(const float* __restrict__ attr,
                            const int*   __restrict__ ei,
                            const float* __restrict__ x,
                            const float* __restrict__ Wk,
                            float*       __restrict__ aggr)
{
    const int lane = threadIdx.x & 63;
    // Per-lane row of W_kernel: W[f=lane][k], k=0..31 (8 KB total, one-time).
    float w[ATTR_D];
#pragma unroll
    for (int k = 0; k < ATTR_D; ++k) w[k] = Wk[lane * ATTR_D + k];

    const int total  = N_EDGES * FEAT;            // 76.8M, fits int32
    const int stride = gridDim.x * blockDim.x;    // multiple of 64
    for (int i = blockIdx.x * blockDim.x + threadIdx.x; i < total; i += stride) {
        const int e   = __builtin_amdgcn_readfirstlane(i >> 6);   // wave-uniform
        const int src = ei[e];
        const int dst = ei[N_EDGES + e];
        const float* __restrict__ arow = attr + (size_t)e * ATTR_D;  // uniform -> s_load
        float a0 = 0.f, a1 = 0.f, a2 = 0.f, a3 = 0.f;
#pragma unroll
        for (int k = 0; k < ATTR_D; k += 4) {
            a0 += arow[k]     * w[k];
            a1 += arow[k + 1] * w[k + 1];
            a2 += arow[k + 2] * w[k + 2];
            a3 += arow[k + 3] * w[k + 3];
        }
        const float kern = (a0 + a1) + (a2 + a3);
        const float msg  = kern * x[src * FEAT + lane];   // coalesced 256B gather
        unsafeAtomicAdd(&aggr[dst * FEAT + lane], msg);   // native global_atomic_add_f32
    }
}

// ---------------------------------------------------------------------------
// One-time transpose of W2 [64][256] -> W2T [256][64] so the node kernel's
// inner f-loop reads contiguous uniform rows.
// ---------------------------------------------------------------------------
__global__ void transpose_w2(const float* __restrict__ W2, float* __restrict__ W2T)
{
    const int t = blockIdx.x * blockDim.x + threadIdx.x;  // t = j*64 + f
    const int j = t >> 6, f = t & 63;
    W2T[t] = W2[f * HID + j];
}

// ---------------------------------------------------------------------------
// Stage 2: per-node LN + MLP + layer_scale + residual. One thread per row.
// io == d_out holds aggr on entry, final output on exit (own-row in-place).
// All weight addresses are wave-uniform -> scalar loads.
// ---------------------------------------------------------------------------
__global__ void node_kernel(const float* __restrict__ x,
                            float*       __restrict__ io,
                            const float* __restrict__ conv_bias,
                            const float* __restrict__ gamma,
                            const float* __restrict__ beta,
                            const float* __restrict__ W1,
                            const float* __restrict__ b1,
                            const float* __restrict__ W2T,
                            const float* __restrict__ b2,
                            const float* __restrict__ ls)
{
    const int n = blockIdx.x * blockDim.x + threadIdx.x;
    if (n >= N_NODES) return;

    float h[FEAT];
    const float* __restrict__ row = io + (size_t)n * FEAT;
#pragma unroll
    for (int k = 0; k < FEAT; ++k) h[k] = row[k] + conv_bias[k];

    // LayerNorm over the 64 features (per-thread, in registers).
    float s0 = 0.f, s1 = 0.f;
#pragma unroll
    for (int k = 0; k < FEAT; k += 2) { s0 += h[k]; s1 += h[k + 1]; }
    const float mu = (s0 + s1) * (1.0f / FEAT);
    float v0 = 0.f, v1 = 0.f;
#pragma unroll
    for (int k = 0; k < FEAT; k += 2) {
        const float d0 = h[k] - mu, d1 = h[k + 1] - mu;
        v0 += d0 * d0; v1 += d1 * d1;
    }
    const float rs = rsqrtf((v0 + v1) * (1.0f / FEAT) + 1e-5f);
#pragma unroll
    for (int k = 0; k < FEAT; ++k) h[k] = (h[k] - mu) * rs * gamma[k] + beta[k];

    // MLP: y1 = relu(h @ W1.T + b1); y2 = y1 @ W2.T + b2 (accumulated).
    float y2[FEAT];
#pragma unroll
    for (int f = 0; f < FEAT; ++f) y2[f] = b2[f];

    for (int j = 0; j < HID; ++j) {
        const float* __restrict__ w1r = W1 + j * FEAT;   // uniform row
        float a0 = 0.f, a1 = 0.f, a2 = 0.f, a3 = 0.f;
#pragma unroll
        for (int k = 0; k < FEAT; k += 4) {
            a0 += h[k]     * w1r[k];
            a1 += h[k + 1] * w1r[k + 1];
            a2 += h[k + 2] * w1r[k + 2];
            a3 += h[k + 3] * w1r[k + 3];
        }
        float y1 = (a0 + a1) + (a2 + a3) + b1[j];
        y1 = fmaxf(y1, 0.f);
        const float* __restrict__ w2r = W2T + j * FEAT;  // uniform row
#pragma unroll
        for (int f = 0; f < FEAT; ++f) y2[f] += y1 * w2r[f];
    }

#pragma unroll
    for (int f = 0; f < FEAT; ++f)
        io[(size_t)n * FEAT + f] = x[(size_t)n * FEAT + f] + ls[f] * y2[f];
}

// ---------------------------------------------------------------------------
extern "C" void kernel_launch(void* const* d_in, const int* in_sizes, int n_in,
                              void* d_out, int out_size, void* d_ws, size_t ws_size,
                              hipStream_t stream)
{
    const float* x     = (const float*)d_in[0];
    const float* attr  = (const float*)d_in[1];
    const int*   ei    = (const int*)d_in[2];
    // d_in[3] = batch (unused)
    const float* Wk    = (const float*)d_in[4];
    const float* cbias = (const float*)d_in[5];
    const float* gamma = (const float*)d_in[6];
    const float* beta  = (const float*)d_in[7];
    const float* W1    = (const float*)d_in[8];
    const float* b1    = (const float*)d_in[9];
    const float* W2    = (const float*)d_in[10];
    const float* b2    = (const float*)d_in[11];
    const float* ls    = (const float*)d_in[12];

    float* out = (float*)d_out;          // used as aggr accumulator, then output
    float* W2T = (float*)d_ws;           // 64 KB scratch

    hipMemsetAsync(d_out, 0, (size_t)N_NODES * FEAT * sizeof(float), stream);
    transpose_w2<<<HID * FEAT / 256, 256, 0, stream>>>(W2, W2T);
    edge_kernel<<<4096, 256, 0, stream>>>(attr, ei, x, Wk, out);
    node_kernel<<<(N_NODES + 255) / 256, 256, 0, stream>>>(
        x, out, cbias, gamma, beta, W1, b1, W2T, b2, ls);
}

// Round 2
// 655.292 us; speedup vs baseline: 1.7115x; 1.7115x over previous
//
#include <hip/hip_runtime.h>
#include <hip/hip_bf16.h>

#define N_NODES 100000
#define N_EDGES 1200000
#define FEAT    64
#define ATTR_D  32
#define HID     256

typedef __attribute__((ext_vector_type(8))) short short8_t;
typedef __attribute__((ext_vector_type(4))) short short4_t;
typedef __attribute__((ext_vector_type(4))) float f32x4;

static __device__ __forceinline__ unsigned short f2bf(float f) {
    unsigned u = __builtin_bit_cast(unsigned, f);
    u += 0x7FFFu + ((u >> 16) & 1u);          // round-to-nearest-even
    return (unsigned short)(u >> 16);
}

// Frag-linear permutation within a 32-element K-block for mfma_f32_16x16x32_bf16:
// lane (l>>4)=hi needs k = 16*half + 4*hi + t as 8 contiguous shorts (j = half*4+t).
static __device__ __forceinline__ int perm32(int k5) {
    return ((k5 >> 2) & 3) * 8 + ((k5 >> 4) & 1) * 4 + (k5 & 3);
}

// ---------------------------------------------------------------------------
// Stage 1: per-edge depthwise kernel + gather-multiply + scatter-add (unchanged).
// ---------------------------------------------------------------------------
__global__ void edge_kernel(const float* __restrict__ attr,
                            const int*   __restrict__ ei,
                            const float* __restrict__ x,
                            const float* __restrict__ Wk,
                            float*       __restrict__ aggr)
{
    const int lane = threadIdx.x & 63;
    float w[ATTR_D];
#pragma unroll
    for (int k = 0; k < ATTR_D; ++k) w[k] = Wk[lane * ATTR_D + k];

    const int total  = N_EDGES * FEAT;
    const int stride = gridDim.x * blockDim.x;
    for (int i = blockIdx.x * blockDim.x + threadIdx.x; i < total; i += stride) {
        const int e   = __builtin_amdgcn_readfirstlane(i >> 6);
        const int src = ei[e];
        const int dst = ei[N_EDGES + e];
        const float* __restrict__ arow = attr + (size_t)e * ATTR_D;
        float a0 = 0.f, a1 = 0.f, a2 = 0.f, a3 = 0.f;
#pragma unroll
        for (int k = 0; k < ATTR_D; k += 4) {
            a0 += arow[k]     * w[k];
            a1 += arow[k + 1] * w[k + 1];
            a2 += arow[k + 2] * w[k + 2];
            a3 += arow[k + 3] * w[k + 3];
        }
        const float kern = (a0 + a1) + (a2 + a3);
        const float msg  = kern * x[src * FEAT + lane];
        unsafeAtomicAdd(&aggr[dst * FEAT + lane], msg);
    }
}

// ---------------------------------------------------------------------------
// One-time: W1 [256][64], W2 [64][256] f32 -> bf16 in frag-linear K-layout.
// ---------------------------------------------------------------------------
__global__ void prep_w(const float* __restrict__ W1, const float* __restrict__ W2,
                       unsigned short* __restrict__ w1b, unsigned short* __restrict__ w2b)
{
    int t = blockIdx.x * blockDim.x + threadIdx.x;     // 0..32767
    if (t < HID * FEAT) {
        int n = t >> 6, k = t & 63;
        int p = (k >> 5) * 32 + perm32(k & 31);
        w1b[n * FEAT + p] = f2bf(W1[t]);
    } else {
        int u = t - HID * FEAT;
        int n = u >> 8, k = u & 255;
        int p = (k >> 5) * 32 + perm32(k & 31);
        w2b[n * HID + p] = f2bf(W2[u]);
    }
}

// ---------------------------------------------------------------------------
// Stage 2: fused LN + MLP + layer_scale + residual via MFMA.
// Block = 256 threads (4 waves) handles 64 nodes, in-place on io (= d_out).
// ---------------------------------------------------------------------------
__global__ __launch_bounds__(256, 3) void node_mfma(
    const float* __restrict__ x, float* __restrict__ io,
    const float* __restrict__ cbias, const float* __restrict__ gam,
    const float* __restrict__ bet,
    const unsigned short* __restrict__ W1b, const float* __restrict__ b1v,
    const unsigned short* __restrict__ W2b, const float* __restrict__ b2v,
    const float* __restrict__ ls)
{
    __shared__ __align__(16) unsigned short Hs[64 * 64];    // 8 KB, swizzled frag-linear
    __shared__ __align__(16) unsigned short Y1s[64 * 256];  // 32 KB, swizzled frag-linear

    const int tid  = threadIdx.x;
    const int w    = tid >> 6;
    const int l    = tid & 63;
    const int lo   = l & 15;
    const int hi   = l >> 4;
    const int base = blockIdx.x * 64;

    // ---------------- LN stage: 4 lanes per row, 16 feats per lane ----------
    {
        const int r    = (w << 4) + (l >> 2);   // 0..63 (tile-local row)
        const int q    = l & 3;                 // feat quarter
        const int node = base + r;
        float v[16];
#pragma unroll
        for (int g = 0; g < 4; ++g) {
            float4 a = {0.f, 0.f, 0.f, 0.f};
            if (node < N_NODES)
                a = ((const float4*)(io + (size_t)node * FEAT + q * 16))[g];
            float4 cb = ((const float4*)(cbias + q * 16))[g];
            v[g*4+0] = a.x + cb.x; v[g*4+1] = a.y + cb.y;
            v[g*4+2] = a.z + cb.z; v[g*4+3] = a.w + cb.w;
        }
        float s = 0.f;
#pragma unroll
        for (int i = 0; i < 16; ++i) s += v[i];
        s += __shfl_xor(s, 1);
        s += __shfl_xor(s, 2);
        const float mu = s * (1.0f / FEAT);
        float vs = 0.f;
#pragma unroll
        for (int i = 0; i < 16; ++i) { float d = v[i] - mu; vs += d * d; }
        vs += __shfl_xor(vs, 1);
        vs += __shfl_xor(vs, 2);
        const float rstd = rsqrtf(vs * (1.0f / FEAT) + 1e-5f);

        unsigned short hs[16];
#pragma unroll
        for (int g = 0; g < 4; ++g) {
            float4 gv = ((const float4*)(gam + q * 16))[g];
            float4 bv = ((const float4*)(bet + q * 16))[g];
            hs[g*4+0] = f2bf((v[g*4+0] - mu) * rstd * gv.x + bv.x);
            hs[g*4+1] = f2bf((v[g*4+1] - mu) * rstd * gv.y + bv.y);
            hs[g*4+2] = f2bf((v[g*4+2] - mu) * rstd * gv.z + bv.z);
            hs[g*4+3] = f2bf((v[g*4+3] - mu) * rstd * gv.w + bv.w);
        }
        // lane q holds k = q*16 + i; frag-linear chunk (8B) per i-group g.
        const int swz = (r & 7) << 4;
#pragma unroll
        for (int g = 0; g < 4; ++g) {
            short4_t p4;
            p4[0] = (short)hs[g*4+0]; p4[1] = (short)hs[g*4+1];
            p4[2] = (short)hs[g*4+2]; p4[3] = (short)hs[g*4+3];
            int off = (((q >> 1) * 64) + g * 16 + (q & 1) * 8) ^ swz;
            *(short4_t*)((char*)Hs + r * 128 + off) = p4;
        }
    }
    __syncthreads();

    // ---------------- GEMM1: Y1[64x256] = H[64x64] @ W1^T, wave = 64 N-cols --
    f32x4 acc1[4][4];
#pragma unroll
    for (int a = 0; a < 4; ++a)
#pragma unroll
        for (int b = 0; b < 4; ++b) acc1[a][b] = (f32x4){0.f, 0.f, 0.f, 0.f};

#pragma unroll
    for (int ks = 0; ks < 2; ++ks) {
        short8_t af[4];
#pragma unroll
        for (int mt = 0; mt < 4; ++mt) {
            int row = mt * 16 + lo;
            int off = (ks * 64 + hi * 16) ^ ((row & 7) << 4);
            af[mt] = *(const short8_t*)((const char*)Hs + row * 128 + off);
        }
#pragma unroll
        for (int nt = 0; nt < 4; ++nt) {
            int n = w * 64 + nt * 16 + lo;
            short8_t bf = *(const short8_t*)(W1b + n * FEAT + ks * 32 + hi * 8);
#pragma unroll
            for (int mt = 0; mt < 4; ++mt)
                acc1[mt][nt] = __builtin_amdgcn_mfma_f32_16x16x32_bf16(
                    af[mt], bf, acc1[mt][nt], 0, 0, 0);
        }
    }

    // b1 + ReLU + bf16 -> Y1 LDS (frag-linear over k=n, swizzled)
#pragma unroll
    for (int nt = 0; nt < 4; ++nt) {
        int n = w * 64 + nt * 16 + lo;
        float b1s = b1v[n];
        int p2 = (n >> 5) * 64 + (lo >> 2) * 16 + ((n >> 4) & 1) * 8 + (lo & 3) * 2;
#pragma unroll
        for (int mt = 0; mt < 4; ++mt) {
#pragma unroll
            for (int rr = 0; rr < 4; ++rr) {
                int row = mt * 16 + hi * 4 + rr;          // D: row=(l>>4)*4+reg
                float y = fmaxf(acc1[mt][nt][rr] + b1s, 0.f);
                int byte = row * 512 + (p2 ^ ((row & 7) << 4));
                *(unsigned short*)((char*)Y1s + byte) = f2bf(y);
            }
        }
    }
    __syncthreads();

    // ---------------- GEMM2: Y2[64x64] = Y1 @ W2^T, wave = 16 M-rows --------
    f32x4 acc2[4];
#pragma unroll
    for (int nt = 0; nt < 4; ++nt) acc2[nt] = (f32x4){0.f, 0.f, 0.f, 0.f};

#pragma unroll
    for (int ks = 0; ks < 8; ++ks) {
        int arow = w * 16 + lo;
        short8_t af = *(const short8_t*)((const char*)Y1s + arow * 512 +
                        ((ks * 64 + hi * 16) ^ ((arow & 7) << 4)));
#pragma unroll
        for (int nt = 0; nt < 4; ++nt) {
            int n = nt * 16 + lo;
            short8_t bf = *(const short8_t*)(W2b + n * HID + ks * 32 + hi * 8);
            acc2[nt] = __builtin_amdgcn_mfma_f32_16x16x32_bf16(af, bf, acc2[nt], 0, 0, 0);
        }
    }

    // ---------------- epilogue: out = x + ls * (y2 + b2) --------------------
#pragma unroll
    for (int nt = 0; nt < 4; ++nt) {
        int col = nt * 16 + lo;
        float lsv = ls[col];
        float b2s = b2v[col];
#pragma unroll
        for (int rr = 0; rr < 4; ++rr) {
            int m = w * 16 + hi * 4 + rr;
            int node = base + m;
            if (node < N_NODES) {
                float y = acc2[nt][rr] + b2s;
                io[(size_t)node * FEAT + col] = x[(size_t)node * FEAT + col] + lsv * y;
            }
        }
    }
}

// ---------------------------------------------------------------------------
extern "C" void kernel_launch(void* const* d_in, const int* in_sizes, int n_in,
                              void* d_out, int out_size, void* d_ws, size_t ws_size,
                              hipStream_t stream)
{
    const float* x     = (const float*)d_in[0];
    const float* attr  = (const float*)d_in[1];
    const int*   ei    = (const int*)d_in[2];
    const float* Wk    = (const float*)d_in[4];
    const float* cbias = (const float*)d_in[5];
    const float* gamma = (const float*)d_in[6];
    const float* beta  = (const float*)d_in[7];
    const float* W1    = (const float*)d_in[8];
    const float* b1    = (const float*)d_in[9];
    const float* W2    = (const float*)d_in[10];
    const float* b2    = (const float*)d_in[11];
    const float* ls    = (const float*)d_in[12];

    float* out = (float*)d_out;                   // aggr accumulator, then output
    unsigned short* w1b = (unsigned short*)d_ws;  // 32 KB
    unsigned short* w2b = w1b + HID * FEAT;       // 32 KB

    hipMemsetAsync(d_out, 0, (size_t)N_NODES * FEAT * sizeof(float), stream);
    prep_w<<<(2 * HID * FEAT) / 256, 256, 0, stream>>>(W1, W2, w1b, w2b);
    edge_kernel<<<4096, 256, 0, stream>>>(attr, ei, x, Wk, out);
    node_mfma<<<(N_NODES + 63) / 64, 256, 0, stream>>>(
        x, out, cbias, gamma, beta, w1b, b1, w2b, b2, ls);
}

// Round 4
// 528.842 us; speedup vs baseline: 2.1208x; 1.2391x over previous
//
#include <hip/hip_runtime.h>

#define N_NODES 100000
#define N_EDGES 1200000
#define FEAT    64
#define ATTR_D  32
#define HID     256
#define NTILES  (N_EDGES / 64)   // 18750 wave-tiles of 64 edges

typedef __attribute__((ext_vector_type(8))) short short8_t;
typedef __attribute__((ext_vector_type(4))) short short4_t;
typedef __attribute__((ext_vector_type(4))) float f32x4;

static __device__ __forceinline__ unsigned short f2bf(float f) {
    unsigned u = __builtin_bit_cast(unsigned, f);
    u += 0x7FFFu + ((u >> 16) & 1u);          // round-to-nearest-even
    return (unsigned short)(u >> 16);
}
static __device__ __forceinline__ float bf2f(unsigned short s) {
    return __builtin_bit_cast(float, (unsigned)s << 16);
}

// Frag-linear permutation within a 32-element K-block for mfma_f32_16x16x32_bf16:
// element j of lane-half hi holds k = 16*(j>>2) + 4*hi + (j&3).
static __device__ __forceinline__ int perm32(int k5) {
    return ((k5 >> 2) & 3) * 8 + ((k5 >> 4) & 1) * 4 + (k5 & 3);
}

// ---------------------------------------------------------------------------
// One-time: W1 [256][64], W2 [64][256], Wk [64][32] f32 -> bf16 frag-linear.
// ---------------------------------------------------------------------------
__global__ void prep_w(const float* __restrict__ W1, const float* __restrict__ W2,
                       const float* __restrict__ Wk,
                       unsigned short* __restrict__ w1b, unsigned short* __restrict__ w2b,
                       unsigned short* __restrict__ wkb)
{
    int t = blockIdx.x * blockDim.x + threadIdx.x;     // 0..34815
    if (t < HID * FEAT) {
        int n = t >> 6, k = t & 63;
        int p = (k >> 5) * 32 + perm32(k & 31);
        w1b[n * FEAT + p] = f2bf(W1[t]);
    } else if (t < 2 * HID * FEAT) {
        int u = t - HID * FEAT;
        int n = u >> 8, k = u & 255;
        int p = (k >> 5) * 32 + perm32(k & 31);
        w2b[n * HID + p] = f2bf(W2[u]);
    } else {
        int u = t - 2 * HID * FEAT;                    // 0..2047
        int n = u >> 5, k = u & 31;
        wkb[n * ATTR_D + perm32(k)] = f2bf(Wk[u]);
    }
}

// ---------------------------------------------------------------------------
// Stage 1: per-64-edge-tile MFMA kernel + gather-multiply + scatter-add.
// Wave handles 64 edges: kern[64x64] = attr[64x32] @ Wk^T via 16 MFMA.
// AGGR_BF16=1: pk_add_bf16 atomics into bf16 aggr (ws); else f32 atomics.
// ---------------------------------------------------------------------------
template<int AGGR_BF16>
__global__ __launch_bounds__(256, 3) void edge_mfma(
    const float* __restrict__ attr, const int* __restrict__ ei,
    const float* __restrict__ x, const unsigned short* __restrict__ wkb,
    unsigned short* __restrict__ aggrb, float* __restrict__ aggrf)
{
    const int w  = threadIdx.x >> 6;
    const int l  = threadIdx.x & 63;
    const int lo = l & 15;
    const int hi = l >> 4;
    const int wt = blockIdx.x * 4 + w;
    if (wt >= NTILES) return;
    const int be = wt * 64;

    // Loop-invariant B-fragments of Wk (frag-linear in ws, L1-resident).
    short8_t bf[4];
#pragma unroll
    for (int nt = 0; nt < 4; ++nt)
        bf[nt] = *(const short8_t*)(wkb + (nt * 16 + lo) * ATTR_D + hi * 8);

    // Edge indices: lane l <-> edge be+l.
    const int s_e = ei[be + l];
    const int d_e = ei[N_EDGES + be + l];

    // A-fragments: edge rows of attr, f32 -> bf16 in-register.
    // Element j needs k = 16*(j>>2) + 4*hi + (j&3): two dwordx4 at cols 4hi, 16+4hi.
    f32x4 acc[4][4];
#pragma unroll
    for (int a = 0; a < 4; ++a)
#pragma unroll
        for (int b = 0; b < 4; ++b) acc[a][b] = (f32x4){0.f, 0.f, 0.f, 0.f};

    short8_t af[4];
#pragma unroll
    for (int mt = 0; mt < 4; ++mt) {
        const size_t r = (size_t)(be + mt * 16 + lo);
        f32x4 u0 = *(const f32x4*)(attr + r * ATTR_D + 4 * hi);
        f32x4 u1 = *(const f32x4*)(attr + r * ATTR_D + 16 + 4 * hi);
        short8_t a;
        a[0] = (short)f2bf(u0[0]); a[1] = (short)f2bf(u0[1]);
        a[2] = (short)f2bf(u0[2]); a[3] = (short)f2bf(u0[3]);
        a[4] = (short)f2bf(u1[0]); a[5] = (short)f2bf(u1[1]);
        a[6] = (short)f2bf(u1[2]); a[7] = (short)f2bf(u1[3]);
        af[mt] = a;
    }
#pragma unroll
    for (int nt = 0; nt < 4; ++nt)
#pragma unroll
        for (int mt = 0; mt < 4; ++mt)
            acc[mt][nt] = __builtin_amdgcn_mfma_f32_16x16x32_bf16(
                af[mt], bf[nt], acc[mt][nt], 0, 0, 0);

    // Epilogue: msg = kern * x[src], scatter-atomic into aggr[dst].
    // D layout: col = nt*16+lo, row m = mt*16 + hi*4 + rr.
#pragma unroll
    for (int mt = 0; mt < 4; ++mt) {
#pragma unroll
        for (int rr = 0; rr < 4; ++rr) {
            const int m  = mt * 16 + hi * 4 + rr;
            const int sv = __shfl(s_e, m);
            const int dv = __shfl(d_e, m);
#pragma unroll
            for (int nt = 0; nt < 4; ++nt) {
                const int c = nt * 16 + lo;
                const float p = acc[mt][nt][rr] * x[(size_t)sv * FEAT + c];
                if (AGGR_BF16) {
                    const float pn = __shfl_xor(p, 1);   // neighbor col's value
                    if ((lo & 1) == 0) {
                        unsigned pk;
                        asm("v_cvt_pk_bf16_f32 %0, %1, %2" : "=v"(pk) : "v"(p), "v"(pn));
                        unsigned short* ap = aggrb + (size_t)dv * FEAT + c;
                        asm volatile("global_atomic_pk_add_bf16 %0, %1, off"
                                     :: "v"(ap), "v"(pk) : "memory");
                    }
                } else {
                    unsafeAtomicAdd(&aggrf[(size_t)dv * FEAT + c], p);
                }
            }
        }
    }
}

// ---------------------------------------------------------------------------
// Stage 2: fused LN + MLP + layer_scale + residual via MFMA (unchanged core).
// AGGR_BF16=1: conv output read from bf16 aggr (ws); else f32 in-place d_out.
// ---------------------------------------------------------------------------
template<int AGGR_BF16>
__global__ __launch_bounds__(256, 3) void node_mfma(
    const float* __restrict__ x, float* __restrict__ io,
    const unsigned short* __restrict__ aggrb,
    const float* __restrict__ cbias, const float* __restrict__ gam,
    const float* __restrict__ bet,
    const unsigned short* __restrict__ W1b, const float* __restrict__ b1v,
    const unsigned short* __restrict__ W2b, const float* __restrict__ b2v,
    const float* __restrict__ ls)
{
    __shared__ __align__(16) unsigned short Hs[64 * 64];    // 8 KB
    __shared__ __align__(16) unsigned short Y1s[64 * 256];  // 32 KB

    const int tid  = threadIdx.x;
    const int w    = tid >> 6;
    const int l    = tid & 63;
    const int lo   = l & 15;
    const int hi   = l >> 4;
    const int base = blockIdx.x * 64;

    // ---------------- LN stage: 4 lanes per row, 16 feats per lane ----------
    {
        const int r    = (w << 4) + (l >> 2);
        const int q    = l & 3;
        const int node = base + r;
        float v[16];
        if (AGGR_BF16) {
            short8_t s0 = {0,0,0,0,0,0,0,0}, s1 = {0,0,0,0,0,0,0,0};
            if (node < N_NODES) {
                const unsigned short* arow = aggrb + (size_t)node * FEAT + q * 16;
                s0 = *(const short8_t*)(arow);
                s1 = *(const short8_t*)(arow + 8);
            }
#pragma unroll
            for (int i = 0; i < 8; ++i) {
                v[i]     = bf2f((unsigned short)s0[i]);
                v[i + 8] = bf2f((unsigned short)s1[i]);
            }
#pragma unroll
            for (int i = 0; i < 16; ++i) v[i] += cbias[q * 16 + i];
        } else {
#pragma unroll
            for (int g = 0; g < 4; ++g) {
                float4 a = {0.f, 0.f, 0.f, 0.f};
                if (node < N_NODES)
                    a = ((const float4*)(io + (size_t)node * FEAT + q * 16))[g];
                float4 cb = ((const float4*)(cbias + q * 16))[g];
                v[g*4+0] = a.x + cb.x; v[g*4+1] = a.y + cb.y;
                v[g*4+2] = a.z + cb.z; v[g*4+3] = a.w + cb.w;
            }
        }
        float s = 0.f;
#pragma unroll
        for (int i = 0; i < 16; ++i) s += v[i];
        s += __shfl_xor(s, 1);
        s += __shfl_xor(s, 2);
        const float mu = s * (1.0f / FEAT);
        float vs = 0.f;
#pragma unroll
        for (int i = 0; i < 16; ++i) { float d = v[i] - mu; vs += d * d; }
        vs += __shfl_xor(vs, 1);
        vs += __shfl_xor(vs, 2);
        const float rstd = rsqrtf(vs * (1.0f / FEAT) + 1e-5f);

        unsigned short hs[16];
#pragma unroll
        for (int g = 0; g < 4; ++g) {
            float4 gv = ((const float4*)(gam + q * 16))[g];
            float4 bv = ((const float4*)(bet + q * 16))[g];
            hs[g*4+0] = f2bf((v[g*4+0] - mu) * rstd * gv.x + bv.x);
            hs[g*4+1] = f2bf((v[g*4+1] - mu) * rstd * gv.y + bv.y);
            hs[g*4+2] = f2bf((v[g*4+2] - mu) * rstd * gv.z + bv.z);
            hs[g*4+3] = f2bf((v[g*4+3] - mu) * rstd * gv.w + bv.w);
        }
        const int swz = (r & 7) << 4;
#pragma unroll
        for (int g = 0; g < 4; ++g) {
            short4_t p4;
            p4[0] = (short)hs[g*4+0]; p4[1] = (short)hs[g*4+1];
            p4[2] = (short)hs[g*4+2]; p4[3] = (short)hs[g*4+3];
            int off = (((q >> 1) * 64) + g * 16 + (q & 1) * 8) ^ swz;
            *(short4_t*)((char*)Hs + r * 128 + off) = p4;
        }
    }
    __syncthreads();

    // ---------------- GEMM1: Y1[64x256] = H @ W1^T, wave = 64 N-cols --------
    f32x4 acc1[4][4];
#pragma unroll
    for (int a = 0; a < 4; ++a)
#pragma unroll
        for (int b = 0; b < 4; ++b) acc1[a][b] = (f32x4){0.f, 0.f, 0.f, 0.f};

#pragma unroll
    for (int ks = 0; ks < 2; ++ks) {
        short8_t af[4];
#pragma unroll
        for (int mt = 0; mt < 4; ++mt) {
            int row = mt * 16 + lo;
            int off = (ks * 64 + hi * 16) ^ ((row & 7) << 4);
            af[mt] = *(const short8_t*)((const char*)Hs + row * 128 + off);
        }
#pragma unroll
        for (int nt = 0; nt < 4; ++nt) {
            int n = w * 64 + nt * 16 + lo;
            short8_t bfr = *(const short8_t*)(W1b + n * FEAT + ks * 32 + hi * 8);
#pragma unroll
            for (int mt = 0; mt < 4; ++mt)
                acc1[mt][nt] = __builtin_amdgcn_mfma_f32_16x16x32_bf16(
                    af[mt], bfr, acc1[mt][nt], 0, 0, 0);
        }
    }

#pragma unroll
    for (int nt = 0; nt < 4; ++nt) {
        int n = w * 64 + nt * 16 + lo;
        float b1s = b1v[n];
        int p2 = (n >> 5) * 64 + (lo >> 2) * 16 + ((n >> 4) & 1) * 8 + (lo & 3) * 2;
#pragma unroll
        for (int mt = 0; mt < 4; ++mt) {
#pragma unroll
            for (int rr = 0; rr < 4; ++rr) {
                int row = mt * 16 + hi * 4 + rr;
                float y = fmaxf(acc1[mt][nt][rr] + b1s, 0.f);
                int byte = row * 512 + (p2 ^ ((row & 7) << 4));
                *(unsigned short*)((char*)Y1s + byte) = f2bf(y);
            }
        }
    }
    __syncthreads();

    // ---------------- GEMM2: Y2[64x64] = Y1 @ W2^T, wave = 16 M-rows --------
    f32x4 acc2[4];
#pragma unroll
    for (int nt = 0; nt < 4; ++nt) acc2[nt] = (f32x4){0.f, 0.f, 0.f, 0.f};

#pragma unroll
    for (int ks = 0; ks < 8; ++ks) {
        int arow = w * 16 + lo;
        short8_t af = *(const short8_t*)((const char*)Y1s + arow * 512 +
                        ((ks * 64 + hi * 16) ^ ((arow & 7) << 4)));
#pragma unroll
        for (int nt = 0; nt < 4; ++nt) {
            int n = nt * 16 + lo;
            short8_t bfr = *(const short8_t*)(W2b + n * HID + ks * 32 + hi * 8);
            acc2[nt] = __builtin_amdgcn_mfma_f32_16x16x32_bf16(af, bfr, acc2[nt], 0, 0, 0);
        }
    }

    // ---------------- epilogue: out = x + ls * (y2 + b2) --------------------
#pragma unroll
    for (int nt = 0; nt < 4; ++nt) {
        int col = nt * 16 + lo;
        float lsv = ls[col];
        float b2s = b2v[col];
#pragma unroll
        for (int rr = 0; rr < 4; ++rr) {
            int m = w * 16 + hi * 4 + rr;
            int node = base + m;
            if (node < N_NODES) {
                float y = acc2[nt][rr] + b2s;
                io[(size_t)node * FEAT + col] = x[(size_t)node * FEAT + col] + lsv * y;
            }
        }
    }
}

// ---------------------------------------------------------------------------
extern "C" void kernel_launch(void* const* d_in, const int* in_sizes, int n_in,
                              void* d_out, int out_size, void* d_ws, size_t ws_size,
                              hipStream_t stream)
{
    const float* x     = (const float*)d_in[0];
    const float* attr  = (const float*)d_in[1];
    const int*   ei    = (const int*)d_in[2];
    const float* Wk    = (const float*)d_in[4];
    const float* cbias = (const float*)d_in[5];
    const float* gamma = (const float*)d_in[6];
    const float* beta  = (const float*)d_in[7];
    const float* W1    = (const float*)d_in[8];
    const float* b1    = (const float*)d_in[9];
    const float* W2    = (const float*)d_in[10];
    const float* b2    = (const float*)d_in[11];
    const float* ls    = (const float*)d_in[12];

    float* out = (float*)d_out;
    unsigned short* w1b = (unsigned short*)d_ws;                 // 32 KB
    unsigned short* w2b = w1b + HID * FEAT;                      // 32 KB
    unsigned short* wkb = w2b + FEAT * HID;                      // 4 KB
    unsigned short* aggrb = (unsigned short*)((char*)d_ws + 128 * 1024);  // 12.8 MB

    const size_t need = 128 * 1024 + (size_t)N_NODES * FEAT * sizeof(unsigned short);
    const bool bf16path = ws_size >= need;

    const int edge_blocks = (NTILES + 3) / 4;     // 4688
    const int node_blocks = (N_NODES + 63) / 64;  // 1563

    prep_w<<<(2 * HID * FEAT + FEAT * ATTR_D) / 256, 256, 0, stream>>>(
        W1, W2, Wk, w1b, w2b, wkb);

    if (bf16path) {
        hipMemsetAsync(aggrb, 0, (size_t)N_NODES * FEAT * sizeof(unsigned short), stream);
        edge_mfma<1><<<edge_blocks, 256, 0, stream>>>(attr, ei, x, wkb, aggrb, out);
        node_mfma<1><<<node_blocks, 256, 0, stream>>>(
            x, out, aggrb, cbias, gamma, beta, w1b, b1, w2b, b2, ls);
    } else {
        hipMemsetAsync(d_out, 0, (size_t)N_NODES * FEAT * sizeof(float), stream);
        edge_mfma<0><<<edge_blocks, 256, 0, stream>>>(attr, ei, x, wkb, aggrb, out);
        node_mfma<0><<<node_blocks, 256, 0, stream>>>(
            x, out, aggrb, cbias, gamma, beta, w1b, b1, w2b, b2, ls);
    }
}

// Round 5
// 513.022 us; speedup vs baseline: 2.1862x; 1.0308x over previous
//
#include <hip/hip_runtime.h>

#define N_NODES 100000
#define N_EDGES 1200000
#define FEAT    64
#define ATTR_D  32
#define HID     256
#define NTILES  (N_EDGES / 64)   // 18750 wave-tiles of 64 edges

typedef __attribute__((ext_vector_type(8))) short short8_t;
typedef __attribute__((ext_vector_type(4))) short short4_t;
typedef __attribute__((ext_vector_type(4))) float f32x4;

static __device__ __forceinline__ unsigned short f2bf(float f) {
    unsigned u = __builtin_bit_cast(unsigned, f);
    u += 0x7FFFu + ((u >> 16) & 1u);          // round-to-nearest-even
    return (unsigned short)(u >> 16);
}
static __device__ __forceinline__ float bf2f(unsigned short s) {
    return __builtin_bit_cast(float, (unsigned)s << 16);
}

// Frag-linear permutation within a 32-element K-block for mfma_f32_16x16x32_bf16:
// element j of lane-half hi holds k = 16*(j>>2) + 4*hi + (j&3).
static __device__ __forceinline__ int perm32(int k5) {
    return ((k5 >> 2) & 3) * 8 + ((k5 >> 4) & 1) * 4 + (k5 & 3);
}

// ---------------------------------------------------------------------------
// One-time: W1 [256][64], W2 [64][256], Wk [64][32] f32 -> bf16 frag-linear.
// ---------------------------------------------------------------------------
__global__ void prep_w(const float* __restrict__ W1, const float* __restrict__ W2,
                       const float* __restrict__ Wk,
                       unsigned short* __restrict__ w1b, unsigned short* __restrict__ w2b,
                       unsigned short* __restrict__ wkb)
{
    int t = blockIdx.x * blockDim.x + threadIdx.x;     // 0..34815
    if (t < HID * FEAT) {
        int n = t >> 6, k = t & 63;
        int p = (k >> 5) * 32 + perm32(k & 31);
        w1b[n * FEAT + p] = f2bf(W1[t]);
    } else if (t < 2 * HID * FEAT) {
        int u = t - HID * FEAT;
        int n = u >> 8, k = u & 255;
        int p = (k >> 5) * 32 + perm32(k & 31);
        w2b[n * HID + p] = f2bf(W2[u]);
    } else {
        int u = t - 2 * HID * FEAT;                    // 0..2047
        int n = u >> 5, k = u & 31;
        wkb[n * ATTR_D + perm32(k)] = f2bf(Wk[u]);
    }
}

// ---------------------------------------------------------------------------
// Stage 1: per-64-edge-tile MFMA kernel + gather-multiply + scatter-add.
// Wave handles 64 edges: kern[64x64] = attr[64x32] @ Wk^T via 16 MFMA.
// Epilogue v2: all 64 x-gathers batch-issued BEFORE the MFMAs (latency hidden
// under MFMA + wave interleave); atomics carry NO memory clobber so the
// compiler may keep loads hoisted. AGGR_BF16=1: pk_add_bf16 into bf16 aggr.
// ---------------------------------------------------------------------------
template<int AGGR_BF16>
__global__ __launch_bounds__(256, 2) void edge_mfma(
    const float* __restrict__ attr, const int* __restrict__ ei,
    const float* __restrict__ x, const unsigned short* __restrict__ wkb,
    unsigned short* __restrict__ aggrb, float* __restrict__ aggrf)
{
    const int w  = threadIdx.x >> 6;
    const int l  = threadIdx.x & 63;
    const int lo = l & 15;
    const int hi = l >> 4;
    const int wt = blockIdx.x * 4 + w;
    if (wt >= NTILES) return;
    const int be = wt * 64;

    // Loop-invariant B-fragments of Wk (frag-linear in ws, cache-resident).
    short8_t bf[4];
#pragma unroll
    for (int nt = 0; nt < 4; ++nt)
        bf[nt] = *(const short8_t*)(wkb + (nt * 16 + lo) * ATTR_D + hi * 8);

    // Edge indices: lane l <-> edge be+l.
    const int s_e = ei[be + l];
    const int d_e = ei[N_EDGES + be + l];

    // A-fragments: edge rows of attr, f32 -> bf16 in-register (issue first).
    f32x4 u0[4], u1[4];
#pragma unroll
    for (int mt = 0; mt < 4; ++mt) {
        const size_t r = (size_t)(be + mt * 16 + lo);
        u0[mt] = *(const f32x4*)(attr + r * ATTR_D + 4 * hi);
        u1[mt] = *(const f32x4*)(attr + r * ATTR_D + 16 + 4 * hi);
    }

    // Rows this lane's D-fragments touch: m = mt*16 + hi*4 + rr.
    int sv[4][4], dvv[4][4];
#pragma unroll
    for (int mt = 0; mt < 4; ++mt)
#pragma unroll
        for (int rr = 0; rr < 4; ++rr) {
            const int m = mt * 16 + hi * 4 + rr;
            sv[mt][rr]  = __shfl(s_e, m);
            dvv[mt][rr] = __shfl(d_e, m);
        }

    // Batch-issue ALL 64 x-gathers; latency hides under MFMAs below.
    float xv[4][4][4];
#pragma unroll
    for (int mt = 0; mt < 4; ++mt)
#pragma unroll
        for (int rr = 0; rr < 4; ++rr)
#pragma unroll
            for (int nt = 0; nt < 4; ++nt)
                xv[mt][rr][nt] = x[(size_t)sv[mt][rr] * FEAT + nt * 16 + lo];

    short8_t af[4];
#pragma unroll
    for (int mt = 0; mt < 4; ++mt) {
        short8_t a;
        a[0] = (short)f2bf(u0[mt][0]); a[1] = (short)f2bf(u0[mt][1]);
        a[2] = (short)f2bf(u0[mt][2]); a[3] = (short)f2bf(u0[mt][3]);
        a[4] = (short)f2bf(u1[mt][0]); a[5] = (short)f2bf(u1[mt][1]);
        a[6] = (short)f2bf(u1[mt][2]); a[7] = (short)f2bf(u1[mt][3]);
        af[mt] = a;
    }

    f32x4 acc[4][4];
#pragma unroll
    for (int a = 0; a < 4; ++a)
#pragma unroll
        for (int b = 0; b < 4; ++b) acc[a][b] = (f32x4){0.f, 0.f, 0.f, 0.f};
#pragma unroll
    for (int nt = 0; nt < 4; ++nt)
#pragma unroll
        for (int mt = 0; mt < 4; ++mt)
            acc[mt][nt] = __builtin_amdgcn_mfma_f32_16x16x32_bf16(
                af[mt], bf[nt], acc[mt][nt], 0, 0, 0);

    // Epilogue: msg = kern * x[src] (registers), scatter-atomic into aggr[dst].
    // D layout: col = nt*16+lo, row m = mt*16 + hi*4 + rr.
#pragma unroll
    for (int mt = 0; mt < 4; ++mt) {
#pragma unroll
        for (int rr = 0; rr < 4; ++rr) {
            const int dv = dvv[mt][rr];
#pragma unroll
            for (int nt = 0; nt < 4; ++nt) {
                const int c = nt * 16 + lo;
                const float p = acc[mt][nt][rr] * xv[mt][rr][nt];
                if (AGGR_BF16) {
                    const float pn = __shfl_xor(p, 1);   // neighbor col's value
                    if ((lo & 1) == 0) {
                        unsigned pk;
                        asm("v_cvt_pk_bf16_f32 %0, %1, %2" : "=v"(pk) : "v"(p), "v"(pn));
                        unsigned short* ap = aggrb + (size_t)dv * FEAT + c;
                        // NOTE: no "memory" clobber — nothing in this kernel
                        // reads aggrb; keeps x-gathers hoistable.
                        asm volatile("global_atomic_pk_add_bf16 %0, %1, off"
                                     :: "v"(ap), "v"(pk));
                    }
                } else {
                    unsafeAtomicAdd(&aggrf[(size_t)dv * FEAT + c], p);
                }
            }
        }
    }
}

// ---------------------------------------------------------------------------
// Stage 2: fused LN + MLP + layer_scale + residual via MFMA (UNCHANGED from
// round 2 — kept byte-identical for attribution; counters expected next round).
// ---------------------------------------------------------------------------
template<int AGGR_BF16>
__global__ __launch_bounds__(256, 3) void node_mfma(
    const float* __restrict__ x, float* __restrict__ io,
    const unsigned short* __restrict__ aggrb,
    const float* __restrict__ cbias, const float* __restrict__ gam,
    const float* __restrict__ bet,
    const unsigned short* __restrict__ W1b, const float* __restrict__ b1v,
    const unsigned short* __restrict__ W2b, const float* __restrict__ b2v,
    const float* __restrict__ ls)
{
    __shared__ __align__(16) unsigned short Hs[64 * 64];    // 8 KB
    __shared__ __align__(16) unsigned short Y1s[64 * 256];  // 32 KB

    const int tid  = threadIdx.x;
    const int w    = tid >> 6;
    const int l    = tid & 63;
    const int lo   = l & 15;
    const int hi   = l >> 4;
    const int base = blockIdx.x * 64;

    // ---------------- LN stage: 4 lanes per row, 16 feats per lane ----------
    {
        const int r    = (w << 4) + (l >> 2);
        const int q    = l & 3;
        const int node = base + r;
        float v[16];
        if (AGGR_BF16) {
            short8_t s0 = {0,0,0,0,0,0,0,0}, s1 = {0,0,0,0,0,0,0,0};
            if (node < N_NODES) {
                const unsigned short* arow = aggrb + (size_t)node * FEAT + q * 16;
                s0 = *(const short8_t*)(arow);
                s1 = *(const short8_t*)(arow + 8);
            }
#pragma unroll
            for (int i = 0; i < 8; ++i) {
                v[i]     = bf2f((unsigned short)s0[i]);
                v[i + 8] = bf2f((unsigned short)s1[i]);
            }
#pragma unroll
            for (int i = 0; i < 16; ++i) v[i] += cbias[q * 16 + i];
        } else {
#pragma unroll
            for (int g = 0; g < 4; ++g) {
                float4 a = {0.f, 0.f, 0.f, 0.f};
                if (node < N_NODES)
                    a = ((const float4*)(io + (size_t)node * FEAT + q * 16))[g];
                float4 cb = ((const float4*)(cbias + q * 16))[g];
                v[g*4+0] = a.x + cb.x; v[g*4+1] = a.y + cb.y;
                v[g*4+2] = a.z + cb.z; v[g*4+3] = a.w + cb.w;
            }
        }
        float s = 0.f;
#pragma unroll
        for (int i = 0; i < 16; ++i) s += v[i];
        s += __shfl_xor(s, 1);
        s += __shfl_xor(s, 2);
        const float mu = s * (1.0f / FEAT);
        float vs = 0.f;
#pragma unroll
        for (int i = 0; i < 16; ++i) { float d = v[i] - mu; vs += d * d; }
        vs += __shfl_xor(vs, 1);
        vs += __shfl_xor(vs, 2);
        const float rstd = rsqrtf(vs * (1.0f / FEAT) + 1e-5f);

        unsigned short hs[16];
#pragma unroll
        for (int g = 0; g < 4; ++g) {
            float4 gv = ((const float4*)(gam + q * 16))[g];
            float4 bv = ((const float4*)(bet + q * 16))[g];
            hs[g*4+0] = f2bf((v[g*4+0] - mu) * rstd * gv.x + bv.x);
            hs[g*4+1] = f2bf((v[g*4+1] - mu) * rstd * gv.y + bv.y);
            hs[g*4+2] = f2bf((v[g*4+2] - mu) * rstd * gv.z + bv.z);
            hs[g*4+3] = f2bf((v[g*4+3] - mu) * rstd * gv.w + bv.w);
        }
        const int swz = (r & 7) << 4;
#pragma unroll
        for (int g = 0; g < 4; ++g) {
            short4_t p4;
            p4[0] = (short)hs[g*4+0]; p4[1] = (short)hs[g*4+1];
            p4[2] = (short)hs[g*4+2]; p4[3] = (short)hs[g*4+3];
            int off = (((q >> 1) * 64) + g * 16 + (q & 1) * 8) ^ swz;
            *(short4_t*)((char*)Hs + r * 128 + off) = p4;
        }
    }
    __syncthreads();

    // ---------------- GEMM1: Y1[64x256] = H @ W1^T, wave = 64 N-cols --------
    f32x4 acc1[4][4];
#pragma unroll
    for (int a = 0; a < 4; ++a)
#pragma unroll
        for (int b = 0; b < 4; ++b) acc1[a][b] = (f32x4){0.f, 0.f, 0.f, 0.f};

#pragma unroll
    for (int ks = 0; ks < 2; ++ks) {
        short8_t af[4];
#pragma unroll
        for (int mt = 0; mt < 4; ++mt) {
            int row = mt * 16 + lo;
            int off = (ks * 64 + hi * 16) ^ ((row & 7) << 4);
            af[mt] = *(const short8_t*)((const char*)Hs + row * 128 + off);
        }
#pragma unroll
        for (int nt = 0; nt < 4; ++nt) {
            int n = w * 64 + nt * 16 + lo;
            short8_t bfr = *(const short8_t*)(W1b + n * FEAT + ks * 32 + hi * 8);
#pragma unroll
            for (int mt = 0; mt < 4; ++mt)
                acc1[mt][nt] = __builtin_amdgcn_mfma_f32_16x16x32_bf16(
                    af[mt], bfr, acc1[mt][nt], 0, 0, 0);
        }
    }

#pragma unroll
    for (int nt = 0; nt < 4; ++nt) {
        int n = w * 64 + nt * 16 + lo;
        float b1s = b1v[n];
        int p2 = (n >> 5) * 64 + (lo >> 2) * 16 + ((n >> 4) & 1) * 8 + (lo & 3) * 2;
#pragma unroll
        for (int mt = 0; mt < 4; ++mt) {
#pragma unroll
            for (int rr = 0; rr < 4; ++rr) {
                int row = mt * 16 + hi * 4 + rr;
                float y = fmaxf(acc1[mt][nt][rr] + b1s, 0.f);
                int byte = row * 512 + (p2 ^ ((row & 7) << 4));
                *(unsigned short*)((char*)Y1s + byte) = f2bf(y);
            }
        }
    }
    __syncthreads();

    // ---------------- GEMM2: Y2[64x64] = Y1 @ W2^T, wave = 16 M-rows --------
    f32x4 acc2[4];
#pragma unroll
    for (int nt = 0; nt < 4; ++nt) acc2[nt] = (f32x4){0.f, 0.f, 0.f, 0.f};

#pragma unroll
    for (int ks = 0; ks < 8; ++ks) {
        int arow = w * 16 + lo;
        short8_t af = *(const short8_t*)((const char*)Y1s + arow * 512 +
                        ((ks * 64 + hi * 16) ^ ((arow & 7) << 4)));
#pragma unroll
        for (int nt = 0; nt < 4; ++nt) {
            int n = nt * 16 + lo;
            short8_t bfr = *(const short8_t*)(W2b + n * HID + ks * 32 + hi * 8);
            acc2[nt] = __builtin_amdgcn_mfma_f32_16x16x32_bf16(af, bfr, acc2[nt], 0, 0, 0);
        }
    }

    // ---------------- epilogue: out = x + ls * (y2 + b2) --------------------
#pragma unroll
    for (int nt = 0; nt < 4; ++nt) {
        int col = nt * 16 + lo;
        float lsv = ls[col];
        float b2s = b2v[col];
#pragma unroll
        for (int rr = 0; rr < 4; ++rr) {
            int m = w * 16 + hi * 4 + rr;
            int node = base + m;
            if (node < N_NODES) {
                float y = acc2[nt][rr] + b2s;
                io[(size_t)node * FEAT + col] = x[(size_t)node * FEAT + col] + lsv * y;
            }
        }
    }
}

// ---------------------------------------------------------------------------
extern "C" void kernel_launch(void* const* d_in, const int* in_sizes, int n_in,
                              void* d_out, int out_size, void* d_ws, size_t ws_size,
                              hipStream_t stream)
{
    const float* x     = (const float*)d_in[0];
    const float* attr  = (const float*)d_in[1];
    const int*   ei    = (const int*)d_in[2];
    const float* Wk    = (const float*)d_in[4];
    const float* cbias = (const float*)d_in[5];
    const float* gamma = (const float*)d_in[6];
    const float* beta  = (const float*)d_in[7];
    const float* W1    = (const float*)d_in[8];
    const float* b1    = (const float*)d_in[9];
    const float* W2    = (const float*)d_in[10];
    const float* b2    = (const float*)d_in[11];
    const float* ls    = (const float*)d_in[12];

    float* out = (float*)d_out;
    unsigned short* w1b = (unsigned short*)d_ws;                 // 32 KB
    unsigned short* w2b = w1b + HID * FEAT;                      // 32 KB
    unsigned short* wkb = w2b + FEAT * HID;                      // 4 KB
    unsigned short* aggrb = (unsigned short*)((char*)d_ws + 128 * 1024);  // 12.8 MB

    const size_t need = 128 * 1024 + (size_t)N_NODES * FEAT * sizeof(unsigned short);
    const bool bf16path = ws_size >= need;

    const int edge_blocks = (NTILES + 3) / 4;     // 4688
    const int node_blocks = (N_NODES + 63) / 64;  // 1563

    prep_w<<<(2 * HID * FEAT + FEAT * ATTR_D) / 256, 256, 0, stream>>>(
        W1, W2, Wk, w1b, w2b, wkb);

    if (bf16path) {
        hipMemsetAsync(aggrb, 0, (size_t)N_NODES * FEAT * sizeof(unsigned short), stream);
        edge_mfma<1><<<edge_blocks, 256, 0, stream>>>(attr, ei, x, wkb, aggrb, out);
        node_mfma<1><<<node_blocks, 256, 0, stream>>>(
            x, out, aggrb, cbias, gamma, beta, w1b, b1, w2b, b2, ls);
    } else {
        hipMemsetAsync(d_out, 0, (size_t)N_NODES * FEAT * sizeof(float), stream);
        edge_mfma<0><<<edge_blocks, 256, 0, stream>>>(attr, ei, x, wkb, aggrb, out);
        node_mfma<0><<<node_blocks, 256, 0, stream>>>(
            x, out, aggrb, cbias, gamma, beta, w1b, b1, w2b, b2, ls);
    }
}